// Round 2
// baseline (974.204 us; speedup 1.0000x reference)
//
#include <hip/hip_runtime.h>
#include <hip/hip_bf16.h>

using bf16 = __hip_bfloat16;
typedef __attribute__((ext_vector_type(8))) short short8;
typedef __attribute__((ext_vector_type(4))) float float4v;

__device__ __forceinline__ float b2f(bf16 x){ return __bfloat162float(x); }
__device__ __forceinline__ bf16  f2b(float x){ return __float2bfloat16(x); }
__device__ __forceinline__ bf16  tob(float x){ return f2b(x); }
__device__ __forceinline__ bf16  tob(bf16 x){ return x; }

#define EPSV 1e-5f

// ------------------------------------------------------------------
// pos prep: posf[r] = {x,y,z,|p|^2} fp32
// ------------------------------------------------------------------
__global__ __launch_bounds__(256) void pos_kernel(const float* __restrict__ pos,
                                                  float* __restrict__ posf, int rows){
  int r = blockIdx.x*256 + threadIdx.x;
  if (r >= rows) return;
  float x = pos[3*r], y = pos[3*r+1], z = pos[3*r+2];
  posf[4*r] = x; posf[4*r+1] = y; posf[4*r+2] = z; posf[4*r+3] = x*x + y*y + z*z;
}

// ------------------------------------------------------------------
// batched 32x32-tiled transpose (+ cast to bf16): out[c][r] = (bf16)in[r][c]
// dims multiples of 32. z-slice offset = z1*s1 + z2*s2, z1=z/Z2.
// ------------------------------------------------------------------
template<typename TI>
__global__ __launch_bounds__(256) void transpose_kernel(
    const TI* __restrict__ in, long ldin, long is1, long is2,
    bf16* __restrict__ out, long ldout, long os1, long os2, int Z2)
{
  int z = blockIdx.z, z1 = z / Z2, z2 = z - z1*Z2;
  in  += (long)z1*is1 + (long)z2*is2;
  out += (long)z1*os1 + (long)z2*os2;
  __shared__ bf16 tile[32][33];
  int tx = threadIdx.x & 31, ty = threadIdx.x >> 5;   // 32 x 8
  long r0 = (long)blockIdx.y*32, c0 = (long)blockIdx.x*32;
#pragma unroll
  for (int i = ty; i < 32; i += 8) tile[i][tx] = tob(in[(r0+i)*ldin + c0 + tx]);
  __syncthreads();
#pragma unroll
  for (int i = ty; i < 32; i += 8) out[(c0+i)*ldout + r0 + tx] = tile[tx][i];
}

// ------------------------------------------------------------------
// LayerNorm over S=256 per row (fp32 in -> bf16 out)
// ------------------------------------------------------------------
__global__ __launch_bounds__(256) void ln_kernel(const float* __restrict__ x,
                                                 const float* __restrict__ g,
                                                 const float* __restrict__ be,
                                                 bf16* __restrict__ out){
  const long row = blockIdx.x;
  const int t = threadIdx.x;
  __shared__ float red[256];
  float v = x[(row<<8) + t];
  red[t] = v; __syncthreads();
  for (int s=128;s>0;s>>=1){ if (t<s) red[t] += red[t+s]; __syncthreads(); }
  const float mu = red[0] * (1.f/256.f);
  __syncthreads();
  const float d = v - mu;
  red[t] = d*d; __syncthreads();
  for (int s=128;s>0;s>>=1){ if (t<s) red[t] += red[t+s]; __syncthreads(); }
  const float rstd = rsqrtf(red[0]*(1.f/256.f) + EPSV);
  out[(row<<8)+t] = f2b(d*rstd*g[t] + be[t]);
}

// ------------------------------------------------------------------
// equivariant vector norm + Wvv mix: per row (b,n), 192 threads
// ------------------------------------------------------------------
__global__ __launch_bounds__(192) void vmix_kernel(const float* __restrict__ vin,
                                                   const float* __restrict__ Wvv,
                                                   const float* __restrict__ vs1,
                                                   bf16* __restrict__ vmix){
  const long row = blockIdx.x;
  const int t = threadIdx.x;
  __shared__ float vv[192], vn[192], nrm[64];
  __shared__ float smean;
  vv[t] = vin[row*192 + t];
  __syncthreads();
  if (t < 64){
    float a = vv[3*t], b = vv[3*t+1], c = vv[3*t+2];
    nrm[t] = sqrtf(a*a + b*b + c*c);
  }
  __syncthreads();
  if (t == 0){ float s = 0.f; for (int i=0;i<64;i++) s += nrm[i]; smean = s*(1.f/64.f); }
  __syncthreads();
  vn[t] = vv[t] / (nrm[t/3] + EPSV) * smean * vs1[t/3];
  __syncthreads();
  const int e = t/3, x = t - 3*e;
  float acc = 0.f;
  for (int c=0;c<64;c++) acc += vn[3*c+x] * Wvv[c*64+e];
  vmix[row*192 + t] = f2b(acc);
}

// ------------------------------------------------------------------
// v2 = v + tv @ Wvo (over c)   (all fp32)
// ------------------------------------------------------------------
__global__ __launch_bounds__(192) void vo_kernel(const float* __restrict__ tv,
                                                 const float* __restrict__ Wvo,
                                                 const float* __restrict__ vin,
                                                 float* __restrict__ v2){
  const long row = blockIdx.x;
  const int t = threadIdx.x;
  __shared__ float tl[192];
  tl[t] = tv[row*192 + t];
  __syncthreads();
  const int e = t/3, x = t - 3*e;
  float acc = 0.f;
  for (int c=0;c<64;c++) acc += tl[3*c+x] * Wvo[c*64+e];
  v2[row*192+t] = vin[row*192+t] + acc;
}

// ------------------------------------------------------------------
// vector FFN: eq-norm2(v2) -> Wfv1 (64->256) -> Wfv2 (256->64) + residual
// fp32 in/out, writes final v output
// ------------------------------------------------------------------
__global__ __launch_bounds__(256) void vffn_kernel(const float* __restrict__ v2,
                                                   const float* __restrict__ vs2,
                                                   const float* __restrict__ Wfv1,
                                                   const float* __restrict__ Wfv2,
                                                   float* __restrict__ vout){
  const long row = blockIdx.x;
  const int t = threadIdx.x;
  __shared__ float vv[192], vn[192], nrm[64], hid[768];
  __shared__ float smean;
  if (t < 192) vv[t] = v2[row*192 + t];
  __syncthreads();
  if (t < 64){
    float a = vv[3*t], b = vv[3*t+1], c = vv[3*t+2];
    nrm[t] = sqrtf(a*a + b*b + c*c);
  }
  __syncthreads();
  if (t == 0){ float s = 0.f; for (int i=0;i<64;i++) s += nrm[i]; smean = s*(1.f/64.f); }
  __syncthreads();
  if (t < 192) vn[t] = vv[t]/(nrm[t/3]+EPSV)*smean*vs2[t/3];
  __syncthreads();
#pragma unroll
  for (int x=0;x<3;x++){
    float a = 0.f;
    for (int c=0;c<64;c++) a += vn[3*c+x]*Wfv1[c*256+t];
    hid[3*t+x] = a;
  }
  __syncthreads();
  if (t < 192){
    const int c = t/3, x = t - 3*c;
    float a = 0.f;
    for (int h=0;h<256;h++) a += hid[3*h+x]*Wfv2[h*64+c];
    vout[row*192+t] = vv[t] + a;
  }
}

// ------------------------------------------------------------------
// fused dist-bias + softplus + softmax, in place on one row of P (len 2048)
// logit = qk*0.125 - softplus(dist(n,m)*w[h] + b[h])
// ------------------------------------------------------------------
__global__ __launch_bounds__(256) void softmax_kernel(bf16* __restrict__ P,
                                                      const float* __restrict__ posf,
                                                      const float* __restrict__ w_dist,
                                                      const float* __restrict__ b_dist){
  const long r = blockIdx.x;            // linear over (b,h,n)
  const int n = (int)(r & 2047);
  const int h = (int)((r >> 11) & 3);
  const int b = (int)(r >> 13);
  bf16* row = P + (((long)(b*4+h)*2048 + n) << 11);
  const float* pn = posf + ((long)b*2048 + n)*4;
  const float xn = pn[0], yn = pn[1], zn = pn[2], p2n = pn[3];
  const float wh = w_dist[h], bh = b_dist[h];
  const int t = threadIdx.x;
  const float* pb = posf + (long)b*2048*4;
  float loc[8];
  float mx = -1e30f;
#pragma unroll
  for (int i=0;i<8;i++){
    const int m = t + (i<<8);
    const float* pm = pb + m*4;
    float d2 = p2n + pm[3] - 2.f*(xn*pm[0] + yn*pm[1] + zn*pm[2]);
    float dist = sqrtf(fmaxf(d2, 1e-12f));
    float arg = dist*wh + bh;
    float sp = (arg > 20.f) ? arg : log1pf(expf(arg));
    float l = b2f(row[m])*0.125f - sp;
    loc[i] = l;
    mx = fmaxf(mx, l);
  }
  __shared__ float red[256];
  red[t] = mx; __syncthreads();
  for (int s=128;s>0;s>>=1){ if (t<s) red[t] = fmaxf(red[t], red[t+s]); __syncthreads(); }
  mx = red[0]; __syncthreads();
  float sum = 0.f;
#pragma unroll
  for (int i=0;i<8;i++){ loc[i] = expf(loc[i]-mx); sum += loc[i]; }
  red[t] = sum; __syncthreads();
  for (int s=128;s>0;s>>=1){ if (t<s) red[t] += red[t+s]; __syncthreads(); }
  const float inv = 1.f/red[0];
#pragma unroll
  for (int i=0;i<8;i++) row[t + (i<<8)] = f2b(loc[i]*inv);
}

// ------------------------------------------------------------------
// attn_mean = mean over 4 heads of P
// ------------------------------------------------------------------
__global__ __launch_bounds__(256) void am_kernel(const bf16* __restrict__ P,
                                                 bf16* __restrict__ AM){
  const long tid = (long)blockIdx.x*256 + threadIdx.x;  // b*N*N + n*N + m
  const long m = tid & 2047, n = (tid>>11) & 2047, b = tid >> 22;
  const long HS = 4194304;                               // 2048*2048
  const long base = b*16777216 + n*2048 + m;
  float s = b2f(P[base]) + b2f(P[base+HS]) + b2f(P[base+2*HS]) + b2f(P[base+3*HS]);
  AM[tid] = f2b(0.25f*s);
}

// ------------------------------------------------------------------
// generic MFMA GEMM: C[i][j] = sum_k A[i][k] * BT[j][k]  (+bias[j]) (+resid)
// one wave per block; wave computes 16 rows x (16*NT) cols.
// 16x16x32 bf16 MFMA; A-frag: A[m=lane&15][k=quad*8+j]; B-frag: BT[n=lane&15][k=quad*8+j];
// D: col=lane&15, row=quad*4+reg.  ACT: 0=none, 1=exact-erf GELU.
// OUTF: 0 = bf16 out, 1 = fp32 out. bias/resid are fp32.
// ------------------------------------------------------------------
template<int NT, int ACT, int OUTF>
__global__ __launch_bounds__(64) void gemm16_kernel(
    const bf16* __restrict__ A, long lda, long As1, long As2,
    const bf16* __restrict__ BT, long ldb, long Bs1, long Bs2,
    const float* __restrict__ bias,
    const float* __restrict__ resid, long ldr, long Rs1, long Rs2,
    void* __restrict__ Cv, long ldc, long Cs1, long Cs2,
    int K, int Z2)
{
  const int z = blockIdx.z;
  const int z1 = z / Z2, z2 = z - z1*Z2;
  A  += (long)z1*As1 + (long)z2*As2;
  BT += (long)z1*Bs1 + (long)z2*Bs2;
  if (resid) resid += (long)z1*Rs1 + (long)z2*Rs2;

  const int lane = threadIdx.x;
  const int col  = lane & 15;
  const int quad = lane >> 4;

  const long rowA = (long)blockIdx.y*16 + col;
  const long colB = (long)blockIdx.x*(16*NT) + col;

  float4v acc[NT];
#pragma unroll
  for (int i=0;i<NT;i++) acc[i] = (float4v){0.f,0.f,0.f,0.f};

  const bf16* aptr = A + rowA*lda + quad*8;
  const bf16* bptr = BT + colB*ldb + quad*8;

  for (int k0 = 0; k0 < K; k0 += 32){
    short8 a = *(const short8*)aptr;
#pragma unroll
    for (int i=0;i<NT;i++){
      short8 b = *(const short8*)(bptr + (long)i*16*ldb);
      acc[i] = __builtin_amdgcn_mfma_f32_16x16x32_bf16(a, b, acc[i], 0, 0, 0);
    }
    aptr += 32; bptr += 32;
  }

  const long rbase = (long)blockIdx.y*16 + quad*4;
#pragma unroll
  for (int i=0;i<NT;i++){
    const long cj = (long)blockIdx.x*(16*NT) + i*16 + col;
    const float bb = bias ? bias[cj] : 0.f;
#pragma unroll
    for (int r=0;r<4;r++){
      const long ci = rbase + r;
      float val = acc[i][r] + bb;
      if (ACT == 1) val = 0.5f*val*(1.f + erff(val*0.70710678118654752f));
      if (resid) val += resid[ci*ldr + cj];
      if (OUTF) ((float*)Cv)[(long)z1*Cs1 + (long)z2*Cs2 + ci*ldc + cj] = val;
      else      ((bf16*)Cv)[(long)z1*Cs1 + (long)z2*Cs2 + ci*ldc + cj] = f2b(val);
    }
  }
}

// ------------------------------------------------------------------
extern "C" void kernel_launch(void* const* d_in, const int* in_sizes, int n_in,
                              void* d_out, int out_size, void* d_ws, size_t ws_size,
                              hipStream_t stream)
{
  const float* s    = (const float*)d_in[0];
  const float* v    = (const float*)d_in[1];
  const float* pos  = (const float*)d_in[2];
  const float* Wq   = (const float*)d_in[3];
  const float* bq   = (const float*)d_in[4];
  const float* Wk   = (const float*)d_in[5];
  const float* bk   = (const float*)d_in[6];
  const float* Wv   = (const float*)d_in[7];
  const float* bv   = (const float*)d_in[8];
  const float* Wo   = (const float*)d_in[9];
  const float* bo   = (const float*)d_in[10];
  const float* w_d  = (const float*)d_in[11];
  const float* b_d  = (const float*)d_in[12];
  const float* Wvv  = (const float*)d_in[13];
  const float* Wvo  = (const float*)d_in[14];
  const float* g1   = (const float*)d_in[15];
  const float* be1  = (const float*)d_in[16];
  const float* vs1  = (const float*)d_in[17];
  const float* g2   = (const float*)d_in[18];
  const float* be2  = (const float*)d_in[19];
  const float* vs2  = (const float*)d_in[20];
  const float* Wf1  = (const float*)d_in[21];
  const float* bf1  = (const float*)d_in[22];
  const float* Wf2  = (const float*)d_in[23];
  const float* bf2  = (const float*)d_in[24];
  const float* Wfv1 = (const float*)d_in[25];
  const float* Wfv2 = (const float*)d_in[26];

  float* outS = (float*)d_out;                      // (4,2048,256)
  float* outV = outS + (size_t)4*2048*256;          // (4,2048,64,3)

  char* w = (char*)d_ws;
  size_t o = 0;
  auto alloc = [&](size_t bytes)->char* {
    char* p = w + o;
    o = (o + bytes + 255) & ~(size_t)255;
    return p;
  };
  float* posf  = (float*)alloc(8192*16);
  bf16* WqT   = (bf16*)alloc(131072);
  bf16* WkT   = (bf16*)alloc(131072);
  bf16* WvT   = (bf16*)alloc(131072);
  bf16* WoT   = (bf16*)alloc(131072);
  bf16* Wf1T  = (bf16*)alloc(524288);
  bf16* Wf2T  = (bf16*)alloc(524288);
  bf16* sn    = (bf16*)alloc(4194304);    // reused for sn2
  bf16* qb    = (bf16*)alloc(4194304);
  bf16* kb    = (bf16*)alloc(4194304);
  bf16* vsb   = (bf16*)alloc(4194304);
  bf16* vsT   = (bf16*)alloc(4194304);
  bf16* sA    = (bf16*)alloc(4194304);
  float* s2   = (float*)alloc(8388608);   // fp32: residual carrier
  bf16* vmix  = (bf16*)alloc(3145728);
  bf16* vmixT = (bf16*)alloc(3145728);
  float* tv   = (float*)alloc(6291456);   // fp32
  float* v2   = (float*)alloc(6291456);   // fp32: residual carrier
  bf16* P     = (bf16*)alloc(134217728);
  bf16* AM    = (bf16*)alloc(33554432);
  bf16* h1    = (bf16*)alloc(16777216);
  if (o > ws_size) return;  // fail loudly (output stays zero -> absmax=max|ref|)

  // --- prep ---
  pos_kernel<<<32, 256, 0, stream>>>(pos, posf, 8192);
  transpose_kernel<float><<<dim3(8,8,1),  256, 0, stream>>>(Wq, 256, 0,0, WqT, 256, 0,0, 1);
  transpose_kernel<float><<<dim3(8,8,1),  256, 0, stream>>>(Wk, 256, 0,0, WkT, 256, 0,0, 1);
  transpose_kernel<float><<<dim3(8,8,1),  256, 0, stream>>>(Wv, 256, 0,0, WvT, 256, 0,0, 1);
  transpose_kernel<float><<<dim3(8,8,1),  256, 0, stream>>>(Wo, 256, 0,0, WoT, 256, 0,0, 1);
  transpose_kernel<float><<<dim3(32,8,1), 256, 0, stream>>>(Wf1, 1024, 0,0, Wf1T, 256, 0,0, 1);
  transpose_kernel<float><<<dim3(8,32,1), 256, 0, stream>>>(Wf2, 256, 0,0, Wf2T, 1024, 0,0, 1);

  // --- norm1 ---
  ln_kernel<<<8192, 256, 0, stream>>>(s, g1, be1, sn);
  vmix_kernel<<<8192, 192, 0, stream>>>(v, Wvv, vs1, vmix);
  transpose_kernel<bf16><<<dim3(6,64,4), 256, 0, stream>>>(vmix, 192, 393216,0, vmixT, 2048, 393216,0, 1);

  // --- QKV projections: M=8192,N=256,K=256 ---
  gemm16_kernel<4,0,0><<<dim3(4,512,1), 64, 0, stream>>>(sn,256,0,0, WqT,256,0,0, bq,
      nullptr,0,0,0, qb,256,0,0, 256, 1);
  gemm16_kernel<4,0,0><<<dim3(4,512,1), 64, 0, stream>>>(sn,256,0,0, WkT,256,0,0, bk,
      nullptr,0,0,0, kb,256,0,0, 256, 1);
  gemm16_kernel<4,0,0><<<dim3(4,512,1), 64, 0, stream>>>(sn,256,0,0, WvT,256,0,0, bv,
      nullptr,0,0,0, vsb,256,0,0, 256, 1);
  transpose_kernel<bf16><<<dim3(2,64,16), 256, 0, stream>>>(vsb, 256, 524288,64, vsT, 2048, 524288,131072, 4);

  // --- logits: per (b,h) 2048x2048, K=64 ---
  gemm16_kernel<4,0,0><<<dim3(32,128,16), 64, 0, stream>>>(qb,256,524288,64, kb,256,524288,64, nullptr,
      nullptr,0,0,0, P,2048,16777216,4194304, 64, 4);

  // --- bias + softmax (in place), head-mean ---
  softmax_kernel<<<32768, 256, 0, stream>>>(P, posf, w_d, b_d);
  am_kernel<<<65536, 256, 0, stream>>>(P, AM);

  // --- PV: per (b,h) 2048x64, K=2048 -> sA (b,n,h*64+d) ---
  gemm16_kernel<4,0,0><<<dim3(1,128,16), 64, 0, stream>>>(P,2048,16777216,4194304, vsT,2048,524288,131072, nullptr,
      nullptr,0,0,0, sA,256,524288,64, 2048, 4);

  // --- output projection + residual: s2 = s + sA@Wo + bo  (fp32 out) ---
  gemm16_kernel<4,0,1><<<dim3(4,512,1), 64, 0, stream>>>(sA,256,0,0, WoT,256,0,0, bo,
      s,256,0,0, s2,256,0,0, 256, 1);

  // --- v_attn: per b, AM(2048x2048) @ vmixT, K=2048 (fp32 out) ---
  gemm16_kernel<4,0,1><<<dim3(3,128,4), 64, 0, stream>>>(AM,2048,4194304,0, vmixT,2048,393216,0, nullptr,
      nullptr,0,0,0, tv,192,393216,0, 2048, 1);
  vo_kernel<<<8192, 192, 0, stream>>>(tv, Wvo, v, v2);

  // --- norm2 + FFN ---
  ln_kernel<<<8192, 256, 0, stream>>>(s2, g2, be2, sn);  // sn := sn2
  gemm16_kernel<4,1,0><<<dim3(16,512,1), 64, 0, stream>>>(sn,256,0,0, Wf1T,256,0,0, bf1,
      nullptr,0,0,0, h1,1024,0,0, 256, 1);
  gemm16_kernel<4,0,1><<<dim3(4,512,1), 64, 0, stream>>>(h1,1024,0,0, Wf2T,1024,0,0, bf2,
      s2,256,0,0, outS,256,0,0, 1024, 1);

  // --- vector FFN + residual -> v output (fp32) ---
  vffn_kernel<<<8192, 256, 0, stream>>>(v2, vs2, Wfv1, Wfv2, outV);
}

// Round 4
// 647.878 us; speedup vs baseline: 1.5037x; 1.5037x over previous
//
#include <hip/hip_runtime.h>
#include <hip/hip_bf16.h>

using bf16 = __hip_bfloat16;
typedef __attribute__((ext_vector_type(8))) short short8;
typedef __attribute__((ext_vector_type(4))) short short4v;
typedef __attribute__((ext_vector_type(4))) float float4v;

__device__ __forceinline__ float b2f(bf16 x){ return __bfloat162float(x); }
__device__ __forceinline__ bf16  f2b(float x){ return __float2bfloat16(x); }
__device__ __forceinline__ bf16  tob(float x){ return f2b(x); }
__device__ __forceinline__ bf16  tob(bf16 x){ return x; }
__device__ __forceinline__ float frcp(float x){ return __builtin_amdgcn_rcpf(x); }

#define EPSV 1e-5f

// ------------------------------------------------------------------
// pos prep: posf[r] = {x,y,z,|p|^2} fp32
// ------------------------------------------------------------------
__global__ __launch_bounds__(256) void pos_kernel(const float* __restrict__ pos,
                                                  float* __restrict__ posf, int rows){
  int r = blockIdx.x*256 + threadIdx.x;
  if (r >= rows) return;
  float x = pos[3*r], y = pos[3*r+1], z = pos[3*r+2];
  posf[4*r] = x; posf[4*r+1] = y; posf[4*r+2] = z; posf[4*r+3] = x*x + y*y + z*z;
}

// ------------------------------------------------------------------
// batched 32x32-tiled transpose (+ cast to bf16)
// ------------------------------------------------------------------
template<typename TI>
__global__ __launch_bounds__(256) void transpose_kernel(
    const TI* __restrict__ in, long ldin, long is1, long is2,
    bf16* __restrict__ out, long ldout, long os1, long os2, int Z2)
{
  int z = blockIdx.z, z1 = z / Z2, z2 = z - z1*Z2;
  in  += (long)z1*is1 + (long)z2*is2;
  out += (long)z1*os1 + (long)z2*os2;
  __shared__ bf16 tile[32][33];
  int tx = threadIdx.x & 31, ty = threadIdx.x >> 5;
  long r0 = (long)blockIdx.y*32, c0 = (long)blockIdx.x*32;
#pragma unroll
  for (int i = ty; i < 32; i += 8) tile[i][tx] = tob(in[(r0+i)*ldin + c0 + tx]);
  __syncthreads();
#pragma unroll
  for (int i = ty; i < 32; i += 8) out[(c0+i)*ldout + r0 + tx] = tile[tx][i];
}

// ------------------------------------------------------------------
// bias concat for fused QKV
// ------------------------------------------------------------------
__global__ __launch_bounds__(256) void bcat_kernel(const float* __restrict__ bq,
                                                   const float* __restrict__ bk,
                                                   const float* __restrict__ bv,
                                                   float* __restrict__ bqkv){
  int j = blockIdx.x*256 + threadIdx.x;
  if (j >= 768) return;
  bqkv[j] = (j < 256) ? bq[j] : (j < 512) ? bk[j-256] : bv[j-512];
}

// ------------------------------------------------------------------
// zero fp32 accumulators (float4 per thread)
// ------------------------------------------------------------------
__global__ __launch_bounds__(256) void zero_kernel(float4v* __restrict__ p, long n4){
  long i = (long)blockIdx.x*256 + threadIdx.x;
  if (i < n4) p[i] = (float4v){0.f,0.f,0.f,0.f};
}

// ------------------------------------------------------------------
// fp32 -> bf16 convert (4 per thread)
// ------------------------------------------------------------------
__global__ __launch_bounds__(256) void cvt_kernel(const float4v* __restrict__ in,
                                                  short4v* __restrict__ out, long n4){
  long i = (long)blockIdx.x*256 + threadIdx.x;
  if (i >= n4) return;
  float4v x = in[i];
  short4v o;
#pragma unroll
  for (int k=0;k<4;k++){ bf16 h = f2b(x[k]); o[k] = *(short*)&h; }
  out[i] = o;
}

// ------------------------------------------------------------------
// LayerNorm over S=256 per row (fp32 in -> bf16 out)
// ------------------------------------------------------------------
__global__ __launch_bounds__(256) void ln_kernel(const float* __restrict__ x,
                                                 const float* __restrict__ g,
                                                 const float* __restrict__ be,
                                                 bf16* __restrict__ out){
  const long row = blockIdx.x;
  const int t = threadIdx.x;
  __shared__ float red[256];
  float v = x[(row<<8) + t];
  red[t] = v; __syncthreads();
  for (int s=128;s>0;s>>=1){ if (t<s) red[t] += red[t+s]; __syncthreads(); }
  const float mu = red[0] * (1.f/256.f);
  __syncthreads();
  const float d = v - mu;
  red[t] = d*d; __syncthreads();
  for (int s=128;s>0;s>>=1){ if (t<s) red[t] += red[t+s]; __syncthreads(); }
  const float rstd = rsqrtf(red[0]*(1.f/256.f) + EPSV);
  out[(row<<8)+t] = f2b(d*rstd*g[t] + be[t]);
}

// ------------------------------------------------------------------
// equivariant vector norm + Wvv mix
// ------------------------------------------------------------------
__global__ __launch_bounds__(192) void vmix_kernel(const float* __restrict__ vin,
                                                   const float* __restrict__ Wvv,
                                                   const float* __restrict__ vs1,
                                                   bf16* __restrict__ vmix){
  const long row = blockIdx.x;
  const int t = threadIdx.x;
  __shared__ float vv[192], vn[192], nrm[64];
  __shared__ float smean;
  vv[t] = vin[row*192 + t];
  __syncthreads();
  if (t < 64){
    float a = vv[3*t], b = vv[3*t+1], c = vv[3*t+2];
    nrm[t] = sqrtf(a*a + b*b + c*c);
  }
  __syncthreads();
  if (t == 0){ float s = 0.f; for (int i=0;i<64;i++) s += nrm[i]; smean = s*(1.f/64.f); }
  __syncthreads();
  vn[t] = vv[t] / (nrm[t/3] + EPSV) * smean * vs1[t/3];
  __syncthreads();
  const int e = t/3, x = t - 3*e;
  float acc = 0.f;
  for (int c=0;c<64;c++) acc += vn[3*c+x] * Wvv[c*64+e];
  vmix[row*192 + t] = f2b(acc);
}

// ------------------------------------------------------------------
// v2 = v + tv @ Wvo
// ------------------------------------------------------------------
__global__ __launch_bounds__(192) void vo_kernel(const float* __restrict__ tv,
                                                 const float* __restrict__ Wvo,
                                                 const float* __restrict__ vin,
                                                 float* __restrict__ v2){
  const long row = blockIdx.x;
  const int t = threadIdx.x;
  __shared__ float tl[192];
  tl[t] = tv[row*192 + t];
  __syncthreads();
  const int e = t/3, x = t - 3*e;
  float acc = 0.f;
  for (int c=0;c<64;c++) acc += tl[3*c+x] * Wvo[c*64+e];
  v2[row*192+t] = vin[row*192+t] + acc;
}

// ------------------------------------------------------------------
// vector FFN (final v output, fp32)
// ------------------------------------------------------------------
__global__ __launch_bounds__(256) void vffn_kernel(const float* __restrict__ v2,
                                                   const float* __restrict__ vs2,
                                                   const float* __restrict__ Wfv1,
                                                   const float* __restrict__ Wfv2,
                                                   float* __restrict__ vout){
  const long row = blockIdx.x;
  const int t = threadIdx.x;
  __shared__ float vv[192], vn[192], nrm[64], hid[768];
  __shared__ float smean;
  if (t < 192) vv[t] = v2[row*192 + t];
  __syncthreads();
  if (t < 64){
    float a = vv[3*t], b = vv[3*t+1], c = vv[3*t+2];
    nrm[t] = sqrtf(a*a + b*b + c*c);
  }
  __syncthreads();
  if (t == 0){ float s = 0.f; for (int i=0;i<64;i++) s += nrm[i]; smean = s*(1.f/64.f); }
  __syncthreads();
  if (t < 192) vn[t] = vv[t]/(nrm[t/3]+EPSV)*smean*vs2[t/3];
  __syncthreads();
#pragma unroll
  for (int x=0;x<3;x++){
    float a = 0.f;
    for (int c=0;c<64;c++) a += vn[3*c+x]*Wfv1[c*256+t];
    hid[3*t+x] = a;
  }
  __syncthreads();
  if (t < 192){
    const int c = t/3, x = t - 3*c;
    float a = 0.f;
    for (int h=0;h<256;h++) a += hid[3*h+x]*Wfv2[h*64+c];
    vout[row*192+t] = vv[t] + a;
  }
}

// ------------------------------------------------------------------
// fused bias+softmax (all 4 heads) + head-mean, one block per (b,n).
// exp(qk/8 - softplus(arg) - mx) == exp(qk/8 - mx) * sigmoid(-arg);
// mx = rowmax(qk/8) is a valid shift since softplus >= 0.
// ------------------------------------------------------------------
__device__ __forceinline__ float block_red(float x, int op, volatile float* wred,
                                           int lane, int wv){
#pragma unroll
  for (int off=32; off; off>>=1){
    float o = __shfl_xor(x, off, 64);
    x = op ? (x+o) : fmaxf(x,o);
  }
  if (lane==0) wred[wv] = x;
  __syncthreads();
  float r = op ? (wred[0]+wred[1]+wred[2]+wred[3])
               : fmaxf(fmaxf(wred[0],wred[1]), fmaxf(wred[2],wred[3]));
  __syncthreads();
  return r;
}

__global__ __launch_bounds__(256) void softmax_am_kernel(
    bf16* __restrict__ P, const float* __restrict__ posf,
    const float* __restrict__ w_dist, const float* __restrict__ b_dist,
    bf16* __restrict__ AM)
{
  const int bn = blockIdx.x;
  const int b = bn >> 11, n = bn & 2047;
  const int t = threadIdx.x;
  const int lane = t & 63, wv = t >> 6;
  __shared__ float wred[4];
  const float* pb = posf + (long)b*8192;
  const float4v pn = *(const float4v*)(pb + 4*n);
  float dist[8], am[8];
#pragma unroll
  for (int i=0;i<8;i++){
    const int m = t + (i<<8);
    const float4v pm = *(const float4v*)(pb + 4*m);
    float d2 = pn[3] + pm[3] - 2.f*(pn[0]*pm[0] + pn[1]*pm[1] + pn[2]*pm[2]);
    dist[i] = sqrtf(fmaxf(d2, 1e-12f));
    am[i] = 0.f;
  }
#pragma unroll
  for (int h=0;h<4;h++){
    bf16* row = P + ((((long)(b*4+h))*2048 + n) << 11);
    const float wh = w_dist[h], bh = b_dist[h];
    float q8[8], mx = -1e30f;
#pragma unroll
    for (int i=0;i<8;i++){
      q8[i] = b2f(row[t + (i<<8)]) * 0.125f;
      mx = fmaxf(mx, q8[i]);
    }
    mx = block_red(mx, 0, wred, lane, wv);
    float p[8], sum = 0.f;
#pragma unroll
    for (int i=0;i<8;i++){
      float sig = frcp(1.f + __expf(dist[i]*wh + bh));
      p[i] = __expf(q8[i] - mx) * sig;
      sum += p[i];
    }
    sum = block_red(sum, 1, wred, lane, wv);
    const float inv = frcp(sum);
#pragma unroll
    for (int i=0;i<8;i++){
      float pv = p[i]*inv;
      row[t + (i<<8)] = f2b(pv);
      am[i] += pv;
    }
  }
  bf16* amrow = AM + ((long)bn << 11);
#pragma unroll
  for (int i=0;i<8;i++) amrow[t + (i<<8)] = f2b(am[i]*0.25f);
}

// ------------------------------------------------------------------
// MFMA GEMM, MT x NT register blocking, optional K-split (KS) with fp32
// atomic epilogue. C[i][j] = sum_k A[i][k]*BT[j][k] (+bias) (+resid).
// OUTM: 0 = bf16 store, 1 = fp32 store, 2 = fp32 unsafeAtomicAdd.
// ACT: 0 = none, 1 = exact-erf GELU.
// ------------------------------------------------------------------
template<int MT, int NT, int ACT, int OUTM>
__global__ __launch_bounds__(64) void gemm_kernel(
    const bf16* __restrict__ A, long lda, long As1, long As2,
    const bf16* __restrict__ BT, long ldb, long Bs1, long Bs2,
    const float* __restrict__ bias,
    const float* __restrict__ resid, long ldr, long Rs1, long Rs2,
    void* __restrict__ Cv, long ldc, long Cs1, long Cs2,
    int K, int Z2, int KS)
{
  int z = blockIdx.z;
  int zz = z / KS, ks = z - zz*KS;
  int z1 = zz / Z2, z2 = zz - z1*Z2;
  A  += (long)z1*As1 + (long)z2*As2 + (long)ks*K;
  BT += (long)z1*Bs1 + (long)z2*Bs2 + (long)ks*K;
  if (resid) resid += (long)z1*Rs1 + (long)z2*Rs2;
  const long cbase = (long)z1*Cs1 + (long)z2*Cs2;

  const int lane = threadIdx.x;
  const int col = lane & 15, quad = lane >> 4;
  const long rowA0 = (long)blockIdx.y*(16*MT);
  const long colB0 = (long)blockIdx.x*(16*NT);

  float4v acc[MT][NT];
#pragma unroll
  for (int m=0;m<MT;m++)
#pragma unroll
    for (int n=0;n<NT;n++) acc[m][n] = (float4v){0.f,0.f,0.f,0.f};

  const bf16* ap[MT];
  const bf16* bp[NT];
#pragma unroll
  for (int m=0;m<MT;m++) ap[m] = A + (rowA0 + m*16 + col)*lda + quad*8;
#pragma unroll
  for (int n=0;n<NT;n++) bp[n] = BT + (colB0 + n*16 + col)*ldb + quad*8;

  for (int k0 = 0; k0 < K; k0 += 32){
    short8 a[MT], bb[NT];
#pragma unroll
    for (int m=0;m<MT;m++){ a[m] = *(const short8*)ap[m]; ap[m] += 32; }
#pragma unroll
    for (int n=0;n<NT;n++){ bb[n] = *(const short8*)bp[n]; bp[n] += 32; }
#pragma unroll
    for (int m=0;m<MT;m++)
#pragma unroll
      for (int n=0;n<NT;n++)
        acc[m][n] = __builtin_amdgcn_mfma_f32_16x16x32_bf16(a[m], bb[n], acc[m][n], 0, 0, 0);
  }

#pragma unroll
  for (int m=0;m<MT;m++){
    const long ri = rowA0 + m*16 + quad*4;
#pragma unroll
    for (int n=0;n<NT;n++){
      const long cj = colB0 + n*16 + col;
      const float bbias = bias ? bias[cj] : 0.f;
#pragma unroll
      for (int r=0;r<4;r++){
        const long ci = ri + r;
        float val = acc[m][n][r] + bbias;
        if (ACT == 1) val = 0.5f*val*(1.f + erff(val*0.70710678118654752f));
        if (resid) val += resid[ci*ldr + cj];
        if (OUTM == 0)      ((bf16*)Cv)[cbase + ci*ldc + cj] = f2b(val);
        else if (OUTM == 1) ((float*)Cv)[cbase + ci*ldc + cj] = val;
        else                unsafeAtomicAdd(&((float*)Cv)[cbase + ci*ldc + cj], val);
      }
    }
  }
}

// ------------------------------------------------------------------
extern "C" void kernel_launch(void* const* d_in, const int* in_sizes, int n_in,
                              void* d_out, int out_size, void* d_ws, size_t ws_size,
                              hipStream_t stream)
{
  const float* s    = (const float*)d_in[0];
  const float* v    = (const float*)d_in[1];
  const float* pos  = (const float*)d_in[2];
  const float* Wq   = (const float*)d_in[3];
  const float* bq   = (const float*)d_in[4];
  const float* Wk   = (const float*)d_in[5];
  const float* bk   = (const float*)d_in[6];
  const float* Wv   = (const float*)d_in[7];
  const float* bv   = (const float*)d_in[8];
  const float* Wo   = (const float*)d_in[9];
  const float* bo   = (const float*)d_in[10];
  const float* w_d  = (const float*)d_in[11];
  const float* b_d  = (const float*)d_in[12];
  const float* Wvv  = (const float*)d_in[13];
  const float* Wvo  = (const float*)d_in[14];
  const float* g1   = (const float*)d_in[15];
  const float* be1  = (const float*)d_in[16];
  const float* vs1  = (const float*)d_in[17];
  const float* g2   = (const float*)d_in[18];
  const float* be2  = (const float*)d_in[19];
  const float* vs2  = (const float*)d_in[20];
  const float* Wf1  = (const float*)d_in[21];
  const float* bf1  = (const float*)d_in[22];
  const float* Wf2  = (const float*)d_in[23];
  const float* bf2  = (const float*)d_in[24];
  const float* Wfv1 = (const float*)d_in[25];
  const float* Wfv2 = (const float*)d_in[26];

  float* outS = (float*)d_out;
  float* outV = outS + (size_t)4*2048*256;

  char* w = (char*)d_ws;
  size_t o = 0;
  auto alloc = [&](size_t bytes)->char* {
    char* p = w + o;
    o = (o + bytes + 255) & ~(size_t)255;
    return p;
  };
  float* posf  = (float*)alloc(131072);
  bf16* WqkvT = (bf16*)alloc(393216);     // 768 x 256
  bf16* WoT   = (bf16*)alloc(131072);
  bf16* Wf1T  = (bf16*)alloc(524288);
  bf16* Wf2T  = (bf16*)alloc(524288);
  float* bqkv = (float*)alloc(3072);
  bf16* sn    = (bf16*)alloc(4194304);    // reused for sn2
  bf16* qkv   = (bf16*)alloc(12582912);   // 8192 x 768
  bf16* vsT   = (bf16*)alloc(4194304);
  bf16* sA    = (bf16*)alloc(4194304);
  float* s2   = (float*)alloc(8388608);
  bf16* vmixT = (bf16*)alloc(3145728);
  float* v2   = (float*)alloc(6291456);
  bf16* P     = (bf16*)alloc(134217728);
  bf16* AM    = (bf16*)alloc(33554432);
  char* accbuf= alloc(23068672);          // sAf + tv; later h1 alias
  float* sAf  = (float*)accbuf;           // 8192x256 fp32 (8.39MB used)
  float* tv   = (float*)(accbuf + 16777216);  // 8192x192 fp32 (6.29MB)
  bf16* vmix  = (bf16*)accbuf;            // alias: dead before accbuf zeroed
  bf16* h1    = (bf16*)accbuf;            // alias: written after sAf dead (tv region untouched by h1? h1=16MB, tv at +16MB: no overlap; tv dead anyway)
  if (o > ws_size) return;

  // --- prep ---
  pos_kernel<<<32, 256, 0, stream>>>(pos, posf, 8192);
  transpose_kernel<float><<<dim3(8,8,1),  256, 0, stream>>>(Wq, 256, 0,0, WqkvT,          256, 0,0, 1);
  transpose_kernel<float><<<dim3(8,8,1),  256, 0, stream>>>(Wk, 256, 0,0, WqkvT + 65536,  256, 0,0, 1);
  transpose_kernel<float><<<dim3(8,8,1),  256, 0, stream>>>(Wv, 256, 0,0, WqkvT + 131072, 256, 0,0, 1);
  transpose_kernel<float><<<dim3(8,8,1),  256, 0, stream>>>(Wo, 256, 0,0, WoT, 256, 0,0, 1);
  transpose_kernel<float><<<dim3(32,8,1), 256, 0, stream>>>(Wf1, 1024, 0,0, Wf1T, 256, 0,0, 1);
  transpose_kernel<float><<<dim3(8,32,1), 256, 0, stream>>>(Wf2, 256, 0,0, Wf2T, 1024, 0,0, 1);
  bcat_kernel<<<3, 256, 0, stream>>>(bq, bk, bv, bqkv);

  // --- norm1 + vector mix ---
  ln_kernel<<<8192, 256, 0, stream>>>(s, g1, be1, sn);
  vmix_kernel<<<8192, 192, 0, stream>>>(v, Wvv, vs1, vmix);
  transpose_kernel<bf16><<<dim3(6,64,4), 256, 0, stream>>>(vmix, 192, 393216,0, vmixT, 2048, 393216,0, 1);

  // --- fused QKV projection: M=8192, N=768, K=256 ---
  gemm_kernel<2,4,0,0><<<dim3(12,256,1), 64, 0, stream>>>(sn,256,0,0, WqkvT,256,0,0, bqkv,
      nullptr,0,0,0, qkv,768,0,0, 256, 1, 1);
  transpose_kernel<bf16><<<dim3(2,64,16), 256, 0, stream>>>(qkv+512, 768, 1572864,64, vsT, 2048, 524288,131072, 4);

  // --- logits: per (b,h) 2048x2048, K=64 ---
  gemm_kernel<2,4,0,0><<<dim3(32,64,16), 64, 0, stream>>>(qkv,768,1572864,64, qkv+256,768,1572864,64, nullptr,
      nullptr,0,0,0, P,2048,16777216,4194304, 64, 4, 1);

  // --- fused dist-bias + softmax + head-mean ---
  softmax_am_kernel<<<8192, 256, 0, stream>>>(P, posf, w_d, b_d, AM);

  // --- zero fp32 accumulators: 23068672 B = 1441792 float4 ---
  zero_kernel<<<5632, 256, 0, stream>>>((float4v*)accbuf, 1441792);

  // --- PV: per (b,h) 2048x64, K=2048, Ksplit=4, atomic fp32 ---
  gemm_kernel<1,4,0,2><<<dim3(1,128,64), 64, 0, stream>>>(P,2048,16777216,4194304, vsT,2048,524288,131072, nullptr,
      nullptr,0,0,0, sAf,256,524288,64, 512, 4, 4);
  cvt_kernel<<<2048, 256, 0, stream>>>((const float4v*)sAf, (short4v*)sA, 524288);

  // --- output projection + residual: s2 = s + sA@Wo + bo (fp32) ---
  gemm_kernel<2,4,0,1><<<dim3(4,256,1), 64, 0, stream>>>(sA,256,0,0, WoT,256,0,0, bo,
      s,256,0,0, s2,256,0,0, 256, 1, 1);

  // --- v_attn: per b, AM(2048x2048)@vmixT, K=2048, Ksplit=4, atomic fp32 ---
  gemm_kernel<2,4,0,2><<<dim3(3,64,16), 64, 0, stream>>>(AM,2048,4194304,0, vmixT,2048,393216,0, nullptr,
      nullptr,0,0,0, tv,192,393216,0, 512, 1, 4);
  vo_kernel<<<8192, 192, 0, stream>>>(tv, Wvo, v, v2);

  // --- norm2 + FFN (h1 aliases accbuf: sAf dead, tv at +16MB untouched) ---
  ln_kernel<<<8192, 256, 0, stream>>>(s2, g2, be2, sn);
  gemm_kernel<2,4,1,0><<<dim3(16,256,1), 64, 0, stream>>>(sn,256,0,0, Wf1T,256,0,0, bf1,
      nullptr,0,0,0, h1,1024,0,0, 256, 1, 1);
  gemm_kernel<2,4,0,1><<<dim3(4,256,1), 64, 0, stream>>>(h1,1024,0,0, Wf2T,1024,0,0, bf2,
      s2,256,0,0, outS,256,0,0, 1024, 1, 1);

  // --- vector FFN -> v output ---
  vffn_kernel<<<8192, 256, 0, stream>>>(v2, vs2, Wfv1, Wfv2, outV);
}

// Round 5
// 564.467 us; speedup vs baseline: 1.7259x; 1.1478x over previous
//
#include <hip/hip_runtime.h>
#include <hip/hip_bf16.h>

using bf16 = __hip_bfloat16;
typedef __attribute__((ext_vector_type(8))) short short8;
typedef __attribute__((ext_vector_type(4))) short short4v;
typedef __attribute__((ext_vector_type(4))) float float4v;

__device__ __forceinline__ float b2f(bf16 x){ return __bfloat162float(x); }
__device__ __forceinline__ bf16  f2b(float x){ return __float2bfloat16(x); }
__device__ __forceinline__ bf16  tob(float x){ return f2b(x); }
__device__ __forceinline__ bf16  tob(bf16 x){ return x; }
__device__ __forceinline__ float frcp(float x){ return __builtin_amdgcn_rcpf(x); }

#define EPSV 1e-5f

// ------------------------------------------------------------------
// pos prep: posf[r] = {x,y,z,|p|^2} fp32
// ------------------------------------------------------------------
__global__ __launch_bounds__(256) void pos_kernel(const float* __restrict__ pos,
                                                  float* __restrict__ posf, int rows){
  int r = blockIdx.x*256 + threadIdx.x;
  if (r >= rows) return;
  float x = pos[3*r], y = pos[3*r+1], z = pos[3*r+2];
  posf[4*r] = x; posf[4*r+1] = y; posf[4*r+2] = z; posf[4*r+3] = x*x + y*y + z*z;
}

// ------------------------------------------------------------------
// all 10 weight transposes (fp32 -> bf16, out[c][r]=in[r][c]) in ONE launch.
// grid (32,32,10); blocks outside a weight's extent early-out.
// ------------------------------------------------------------------
struct WTDesc { const float* src; bf16* dst; int rows, cols; };
struct WTPack { WTDesc d[10]; };

__global__ __launch_bounds__(256) void wtrans_kernel(WTPack p){
  WTDesc w = p.d[blockIdx.z];
  long r0 = (long)blockIdx.y*32, c0 = (long)blockIdx.x*32;
  if (r0 >= w.rows || c0 >= w.cols) return;
  __shared__ bf16 tile[32][33];
  int tx = threadIdx.x & 31, ty = threadIdx.x >> 5;
#pragma unroll
  for (int i = ty; i < 32; i += 8) tile[i][tx] = f2b(w.src[(r0+i)*w.cols + c0 + tx]);
  __syncthreads();
#pragma unroll
  for (int i = ty; i < 32; i += 8) w.dst[(c0+i)*w.rows + r0 + tx] = tile[tx][i];
}

// ------------------------------------------------------------------
// batched 32x32-tiled transpose (+ cast to bf16)
// ------------------------------------------------------------------
template<typename TI>
__global__ __launch_bounds__(256) void transpose_kernel(
    const TI* __restrict__ in, long ldin, long is1, long is2,
    bf16* __restrict__ out, long ldout, long os1, long os2, int Z2)
{
  int z = blockIdx.z, z1 = z / Z2, z2 = z - z1*Z2;
  in  += (long)z1*is1 + (long)z2*is2;
  out += (long)z1*os1 + (long)z2*os2;
  __shared__ bf16 tile[32][33];
  int tx = threadIdx.x & 31, ty = threadIdx.x >> 5;
  long r0 = (long)blockIdx.y*32, c0 = (long)blockIdx.x*32;
#pragma unroll
  for (int i = ty; i < 32; i += 8) tile[i][tx] = tob(in[(r0+i)*ldin + c0 + tx]);
  __syncthreads();
#pragma unroll
  for (int i = ty; i < 32; i += 8) out[(c0+i)*ldout + r0 + tx] = tile[tx][i];
}

// ------------------------------------------------------------------
// bias concat for fused QKV
// ------------------------------------------------------------------
__global__ __launch_bounds__(256) void bcat_kernel(const float* __restrict__ bq,
                                                   const float* __restrict__ bk,
                                                   const float* __restrict__ bv,
                                                   float* __restrict__ bqkv){
  int j = blockIdx.x*256 + threadIdx.x;
  if (j >= 768) return;
  bqkv[j] = (j < 256) ? bq[j] : (j < 512) ? bk[j-256] : bv[j-512];
}

// ------------------------------------------------------------------
// zero fp32 accumulators (float4 per thread)
// ------------------------------------------------------------------
__global__ __launch_bounds__(256) void zero_kernel(float4v* __restrict__ p, long n4){
  long i = (long)blockIdx.x*256 + threadIdx.x;
  if (i < n4) p[i] = (float4v){0.f,0.f,0.f,0.f};
}

// ------------------------------------------------------------------
// fp32 -> bf16 convert (4 per thread)
// ------------------------------------------------------------------
__global__ __launch_bounds__(256) void cvt_kernel(const float4v* __restrict__ in,
                                                  short4v* __restrict__ out, long n4){
  long i = (long)blockIdx.x*256 + threadIdx.x;
  if (i >= n4) return;
  float4v x = in[i];
  short4v o;
#pragma unroll
  for (int k=0;k<4;k++){ bf16 h = f2b(x[k]); o[k] = *(short*)&h; }
  out[i] = o;
}

// ------------------------------------------------------------------
// LayerNorm over S=256 per row, one-pass sum/sumsq (fp32 in -> bf16 out)
// ------------------------------------------------------------------
__global__ __launch_bounds__(256) void ln_kernel(const float* __restrict__ x,
                                                 const float* __restrict__ g,
                                                 const float* __restrict__ be,
                                                 bf16* __restrict__ out){
  const long row = blockIdx.x;
  const int t = threadIdx.x;
  __shared__ float r1[256], r2[256];
  float v = x[(row<<8) + t];
  r1[t] = v; r2[t] = v*v; __syncthreads();
  for (int s=128;s>0;s>>=1){
    if (t<s){ r1[t] += r1[t+s]; r2[t] += r2[t+s]; }
    __syncthreads();
  }
  const float mu = r1[0] * (1.f/256.f);
  const float var = r2[0] * (1.f/256.f) - mu*mu;
  const float rstd = rsqrtf(fmaxf(var, 0.f) + EPSV);
  out[(row<<8)+t] = f2b((v-mu)*rstd*g[t] + be[t]);
}

// ------------------------------------------------------------------
// eq-norm 1: v (b,n,c,x) fp32 -> vnX[(b,n,x), c] bf16   (X layout for GEMM)
// ------------------------------------------------------------------
__global__ __launch_bounds__(192) void vnorm1_kernel(const float* __restrict__ vin,
                                                     const float* __restrict__ vs1,
                                                     bf16* __restrict__ vnX){
  const long row = blockIdx.x;         // bn
  const int t = threadIdx.x;           // c*3+x
  __shared__ float vv[192], nrm[64];
  __shared__ float smean;
  vv[t] = vin[row*192 + t];
  __syncthreads();
  if (t < 64){
    float a = vv[3*t], b = vv[3*t+1], c = vv[3*t+2];
    nrm[t] = sqrtf(a*a + b*b + c*c);
  }
  __syncthreads();
  if (t == 0){ float s = 0.f; for (int i=0;i<64;i++) s += nrm[i]; smean = s*(1.f/64.f); }
  __syncthreads();
  const int c = t/3, x = t - 3*c;
  const float val = vv[t] / (nrm[c] + EPSV) * smean * vs1[c];
  vnX[row*192 + x*64 + c] = f2b(val);
}

// ------------------------------------------------------------------
// eq-norm 2: v2X[(b,n), x*64+c] fp32 -> vn2X same layout bf16
// ------------------------------------------------------------------
__global__ __launch_bounds__(192) void vnorm2_kernel(const float* __restrict__ v2X,
                                                     const float* __restrict__ vs2,
                                                     bf16* __restrict__ vn2X){
  const long row = blockIdx.x;
  const int t = threadIdx.x;           // x*64+c
  __shared__ float vv[192], nrm[64];
  __shared__ float smean;
  vv[t] = v2X[row*192 + t];
  __syncthreads();
  if (t < 64){
    float a = vv[t], b = vv[t+64], c = vv[t+128];
    nrm[t] = sqrtf(a*a + b*b + c*c);
  }
  __syncthreads();
  if (t == 0){ float s = 0.f; for (int i=0;i<64;i++) s += nrm[i]; smean = s*(1.f/64.f); }
  __syncthreads();
  const int c = t & 63;
  vn2X[row*192 + t] = f2b(vv[t] / (nrm[c] + EPSV) * smean * vs2[c]);
}

// ------------------------------------------------------------------
// fused bias+softmax (all 4 heads) + head-mean, one block per (b,n).
// exp(qk/8 - softplus(arg) - mx) == exp(qk/8 - mx) * sigmoid(-arg)
// ------------------------------------------------------------------
__device__ __forceinline__ float block_red(float x, int op, volatile float* wred,
                                           int lane, int wv){
#pragma unroll
  for (int off=32; off; off>>=1){
    float o = __shfl_xor(x, off, 64);
    x = op ? (x+o) : fmaxf(x,o);
  }
  if (lane==0) wred[wv] = x;
  __syncthreads();
  float r = op ? (wred[0]+wred[1]+wred[2]+wred[3])
               : fmaxf(fmaxf(wred[0],wred[1]), fmaxf(wred[2],wred[3]));
  __syncthreads();
  return r;
}

__global__ __launch_bounds__(256) void softmax_am_kernel(
    bf16* __restrict__ P, const float* __restrict__ posf,
    const float* __restrict__ w_dist, const float* __restrict__ b_dist,
    bf16* __restrict__ AM)
{
  const int bn = blockIdx.x;
  const int b = bn >> 11, n = bn & 2047;
  const int t = threadIdx.x;
  const int lane = t & 63, wv = t >> 6;
  __shared__ float wred[4];
  const float* pb = posf + (long)b*8192;
  const float4v pn = *(const float4v*)(pb + 4*n);
  float dist[8], am[8];
#pragma unroll
  for (int i=0;i<8;i++){
    const int m = t + (i<<8);
    const float4v pm = *(const float4v*)(pb + 4*m);
    float d2 = pn[3] + pm[3] - 2.f*(pn[0]*pm[0] + pn[1]*pm[1] + pn[2]*pm[2]);
    dist[i] = sqrtf(fmaxf(d2, 1e-12f));
    am[i] = 0.f;
  }
#pragma unroll
  for (int h=0;h<4;h++){
    bf16* row = P + ((((long)(b*4+h))*2048 + n) << 11);
    const float wh = w_dist[h], bh = b_dist[h];
    float q8[8], mx = -1e30f;
#pragma unroll
    for (int i=0;i<8;i++){
      q8[i] = b2f(row[t + (i<<8)]) * 0.125f;
      mx = fmaxf(mx, q8[i]);
    }
    mx = block_red(mx, 0, wred, lane, wv);
    float p[8], sum = 0.f;
#pragma unroll
    for (int i=0;i<8;i++){
      float sig = frcp(1.f + __expf(dist[i]*wh + bh));
      p[i] = __expf(q8[i] - mx) * sig;
      sum += p[i];
    }
    sum = block_red(sum, 1, wred, lane, wv);
    const float inv = frcp(sum);
#pragma unroll
    for (int i=0;i<8;i++){
      float pv = p[i]*inv;
      row[t + (i<<8)] = f2b(pv);
      am[i] += pv;
    }
  }
  bf16* amrow = AM + ((long)bn << 11);
#pragma unroll
  for (int i=0;i<8;i++) amrow[t + (i<<8)] = f2b(am[i]*0.25f);
}

// ------------------------------------------------------------------
// MFMA GEMM, MT x NT register blocking, optional K-split (KS) with fp32
// atomic epilogue. C[i][j] = sum_k A[i][k]*BT[j][k] (+bias) (+resid).
// OUTM: 0 = bf16 store, 1 = fp32 store, 2 = fp32 unsafeAtomicAdd.
// ACT: 0 = none, 1 = exact-erf GELU.
// RXIL/CXIL: x-interleaved (b,n,c,x) addressing for resid read / C store,
// where row ci = bn*3+x, col cj = c: addr = (ci/3)*192 + cj*3 + ci%3.
// ------------------------------------------------------------------
template<int MT, int NT, int ACT, int OUTM, int RXIL, int CXIL>
__global__ __launch_bounds__(64) void gemm_kernel(
    const bf16* __restrict__ A, long lda, long As1, long As2,
    const bf16* __restrict__ BT, long ldb, long Bs1, long Bs2,
    const float* __restrict__ bias,
    const float* __restrict__ resid, long ldr, long Rs1, long Rs2,
    void* __restrict__ Cv, long ldc, long Cs1, long Cs2,
    int K, int Z2, int KS)
{
  int z = blockIdx.z;
  int zz = z / KS, ks = z - zz*KS;
  int z1 = zz / Z2, z2 = zz - z1*Z2;
  A  += (long)z1*As1 + (long)z2*As2 + (long)ks*K;
  BT += (long)z1*Bs1 + (long)z2*Bs2 + (long)ks*K;
  if (resid) resid += (long)z1*Rs1 + (long)z2*Rs2;
  const long cbase = (long)z1*Cs1 + (long)z2*Cs2;

  const int lane = threadIdx.x;
  const int col = lane & 15, quad = lane >> 4;
  const long rowA0 = (long)blockIdx.y*(16*MT);
  const long colB0 = (long)blockIdx.x*(16*NT);

  float4v acc[MT][NT];
#pragma unroll
  for (int m=0;m<MT;m++)
#pragma unroll
    for (int n=0;n<NT;n++) acc[m][n] = (float4v){0.f,0.f,0.f,0.f};

  const bf16* ap[MT];
  const bf16* bp[NT];
#pragma unroll
  for (int m=0;m<MT;m++) ap[m] = A + (rowA0 + m*16 + col)*lda + quad*8;
#pragma unroll
  for (int n=0;n<NT;n++) bp[n] = BT + (colB0 + n*16 + col)*ldb + quad*8;

  for (int k0 = 0; k0 < K; k0 += 32){
    short8 a[MT], bb[NT];
#pragma unroll
    for (int m=0;m<MT;m++){ a[m] = *(const short8*)ap[m]; ap[m] += 32; }
#pragma unroll
    for (int n=0;n<NT;n++){ bb[n] = *(const short8*)bp[n]; bp[n] += 32; }
#pragma unroll
    for (int m=0;m<MT;m++)
#pragma unroll
      for (int n=0;n<NT;n++)
        acc[m][n] = __builtin_amdgcn_mfma_f32_16x16x32_bf16(a[m], bb[n], acc[m][n], 0, 0, 0);
  }

#pragma unroll
  for (int m=0;m<MT;m++){
    const long ri = rowA0 + m*16 + quad*4;
#pragma unroll
    for (int n=0;n<NT;n++){
      const long cj = colB0 + n*16 + col;
      const float bbias = bias ? bias[cj] : 0.f;
#pragma unroll
      for (int r=0;r<4;r++){
        const long ci = ri + r;
        float val = acc[m][n][r] + bbias;
        if (ACT == 1) val = 0.5f*val*(1.f + erff(val*0.70710678118654752f));
        if (resid){
          const long raddr = RXIL ? ((ci/3)*192 + cj*3 + (ci%3)) : (ci*ldr + cj);
          val += resid[raddr];
        }
        const long caddr = CXIL ? (cbase + (ci/3)*192 + cj*3 + (ci%3))
                                : (cbase + ci*ldc + cj);
        if (OUTM == 0)      ((bf16*)Cv)[caddr] = f2b(val);
        else if (OUTM == 1) ((float*)Cv)[caddr] = val;
        else                unsafeAtomicAdd(&((float*)Cv)[caddr], val);
      }
    }
  }
}

// ------------------------------------------------------------------
extern "C" void kernel_launch(void* const* d_in, const int* in_sizes, int n_in,
                              void* d_out, int out_size, void* d_ws, size_t ws_size,
                              hipStream_t stream)
{
  const float* s    = (const float*)d_in[0];
  const float* v    = (const float*)d_in[1];
  const float* pos  = (const float*)d_in[2];
  const float* Wq   = (const float*)d_in[3];
  const float* bq   = (const float*)d_in[4];
  const float* Wk   = (const float*)d_in[5];
  const float* bk   = (const float*)d_in[6];
  const float* Wv   = (const float*)d_in[7];
  const float* bv   = (const float*)d_in[8];
  const float* Wo   = (const float*)d_in[9];
  const float* bo   = (const float*)d_in[10];
  const float* w_d  = (const float*)d_in[11];
  const float* b_d  = (const float*)d_in[12];
  const float* Wvv  = (const float*)d_in[13];
  const float* Wvo  = (const float*)d_in[14];
  const float* g1   = (const float*)d_in[15];
  const float* be1  = (const float*)d_in[16];
  const float* vs1  = (const float*)d_in[17];
  const float* g2   = (const float*)d_in[18];
  const float* be2  = (const float*)d_in[19];
  const float* vs2  = (const float*)d_in[20];
  const float* Wf1  = (const float*)d_in[21];
  const float* bf1  = (const float*)d_in[22];
  const float* Wf2  = (const float*)d_in[23];
  const float* bf2  = (const float*)d_in[24];
  const float* Wfv1 = (const float*)d_in[25];
  const float* Wfv2 = (const float*)d_in[26];

  float* outS = (float*)d_out;
  float* outV = outS + (size_t)4*2048*256;

  char* w = (char*)d_ws;
  size_t o = 0;
  auto alloc = [&](size_t bytes)->char* {
    char* p = w + o;
    o = (o + bytes + 255) & ~(size_t)255;
    return p;
  };
  float* posf  = (float*)alloc(131072);
  bf16* WqkvT = (bf16*)alloc(393216);       // 768 x 256
  bf16* WoT   = (bf16*)alloc(131072);
  bf16* Wf1T  = (bf16*)alloc(524288);
  bf16* Wf2T  = (bf16*)alloc(524288);
  bf16* WvvT  = (bf16*)alloc(8192);
  bf16* WvoT  = (bf16*)alloc(8192);
  bf16* Wfv1T = (bf16*)alloc(32768);        // 256 x 64
  bf16* Wfv2T = (bf16*)alloc(32768);        // 64 x 256
  float* bqkv = (float*)alloc(3072);
  bf16* sn    = (bf16*)alloc(4194304);      // reused for sn2
  bf16* qkv   = (bf16*)alloc(12582912);     // 8192 x 768; later alias: hv (24576x256)
  bf16* vsT   = (bf16*)alloc(4194304);
  bf16* sA    = (bf16*)alloc(4194304);
  float* s2   = (float*)alloc(8388608);
  bf16* vnX   = (bf16*)alloc(3145728);      // 24576 x 64; later alias: vn2X
  bf16* vmixX = (bf16*)alloc(3145728);      // 24576 x 64; later alias: tvXb
  bf16* vmixXT= (bf16*)alloc(3145728);      // (b, 192, 2048)
  float* v2X  = (float*)alloc(6291456);     // 24576 x 64 fp32
  bf16* P     = (bf16*)alloc(134217728);    // later alias: h1 (8192x1024 bf16)
  bf16* AM    = (bf16*)alloc(33554432);
  char* accbuf= alloc(14680064);            // sAf (8.39MB) + tvX (6.29MB)
  float* sAf  = (float*)accbuf;
  float* tvX  = (float*)(accbuf + 8388608);
  bf16* vn2X  = vnX;                        // vnX dead after vmixX GEMM
  bf16* tvXb  = vmixX;                      // vmixX dead after its transpose
  bf16* hv    = qkv;                        // qkv dead after logits GEMM
  bf16* h1    = P;                          // P dead after PV GEMM
  if (o > ws_size) return;

  // --- prep: pos + all 10 weight transposes in one launch + bias concat ---
  pos_kernel<<<32, 256, 0, stream>>>(pos, posf, 8192);
  WTPack pk;
  pk.d[0] = {Wq,   WqkvT,          256, 256};
  pk.d[1] = {Wk,   WqkvT + 65536,  256, 256};
  pk.d[2] = {Wv,   WqkvT + 131072, 256, 256};
  pk.d[3] = {Wo,   WoT,            256, 256};
  pk.d[4] = {Wf1,  Wf1T,           256, 1024};
  pk.d[5] = {Wf2,  Wf2T,           1024, 256};
  pk.d[6] = {Wvv,  WvvT,           64, 64};
  pk.d[7] = {Wvo,  WvoT,           64, 64};
  pk.d[8] = {Wfv1, Wfv1T,          64, 256};
  pk.d[9] = {Wfv2, Wfv2T,          256, 64};
  wtrans_kernel<<<dim3(32,32,10), 256, 0, stream>>>(pk);
  bcat_kernel<<<3, 256, 0, stream>>>(bq, bk, bv, bqkv);

  // --- norm1 (scalar + vector) ---
  ln_kernel<<<8192, 256, 0, stream>>>(s, g1, be1, sn);
  vnorm1_kernel<<<8192, 192, 0, stream>>>(v, vs1, vnX);

  // --- vmixX = vnX @ WvvT: (24576 x 64), K=64 ---
  gemm_kernel<2,4,0,0,0,0><<<dim3(1,768,1), 64, 0, stream>>>(vnX,64,0,0, WvvT,64,0,0,
      nullptr, nullptr,0,0,0, vmixX,64,0,0, 64, 1, 1);
  // per-b transpose (2048 x 192) -> vmixXT (b, 192, 2048)
  transpose_kernel<bf16><<<dim3(6,64,4), 256, 0, stream>>>(vmixX, 192, 393216,0,
      vmixXT, 2048, 393216,0, 1);

  // --- fused QKV projection: M=8192, N=768, K=256 ---
  gemm_kernel<2,4,0,0,0,0><<<dim3(12,256,1), 64, 0, stream>>>(sn,256,0,0, WqkvT,256,0,0,
      bqkv, nullptr,0,0,0, qkv,768,0,0, 256, 1, 1);
  transpose_kernel<bf16><<<dim3(2,64,16), 256, 0, stream>>>(qkv+512, 768, 1572864,64,
      vsT, 2048, 524288,131072, 4);

  // --- logits: per (b,h) 2048x2048, K=64 ---
  gemm_kernel<2,4,0,0,0,0><<<dim3(32,64,16), 64, 0, stream>>>(qkv,768,1572864,64,
      qkv+256,768,1572864,64, nullptr, nullptr,0,0,0, P,2048,16777216,4194304, 64, 4, 1);

  // --- fused dist-bias + softmax + head-mean ---
  softmax_am_kernel<<<8192, 256, 0, stream>>>(P, posf, w_d, b_d, AM);

  // --- zero fp32 accumulators: 14680064 B = 917504 float4 ---
  zero_kernel<<<3584, 256, 0, stream>>>((float4v*)accbuf, 917504);

  // --- PV: per (b,h) 2048x64, K=2048, Ksplit=4, atomic fp32 ---
  gemm_kernel<1,4,0,2,0,0><<<dim3(1,128,64), 64, 0, stream>>>(P,2048,16777216,4194304,
      vsT,2048,524288,131072, nullptr, nullptr,0,0,0, sAf,256,524288,64, 512, 4, 4);

  // --- v_attn: per b, AM(2048x2048) @ vmixXT, K=2048, Ksplit=4, atomic fp32 ---
  gemm_kernel<2,4,0,2,0,0><<<dim3(3,64,16), 64, 0, stream>>>(AM,2048,4194304,0,
      vmixXT,2048,393216,0, nullptr, nullptr,0,0,0, tvX,192,393216,0, 512, 1, 4);

  cvt_kernel<<<2048, 256, 0, stream>>>((const float4v*)sAf, (short4v*)sA, 524288);
  cvt_kernel<<<1536, 256, 0, stream>>>((const float4v*)tvX, (short4v*)tvXb, 393216);

  // --- output projection + residual: s2 = s + sA@Wo + bo (fp32) ---
  gemm_kernel<2,4,0,1,0,0><<<dim3(4,256,1), 64, 0, stream>>>(sA,256,0,0, WoT,256,0,0,
      bo, s,256,0,0, s2,256,0,0, 256, 1, 1);

  // --- v2X = v (interleaved resid) + tvXb @ WvoT: (24576 x 64), K=64 ---
  gemm_kernel<2,4,0,1,1,0><<<dim3(1,768,1), 64, 0, stream>>>(tvXb,64,0,0, WvoT,64,0,0,
      nullptr, v,0,0,0, v2X,64,0,0, 64, 1, 1);

  // --- norm2 + FFN (h1 aliases P: P dead after PV GEMM) ---
  ln_kernel<<<8192, 256, 0, stream>>>(s2, g2, be2, sn);
  gemm_kernel<2,4,1,0,0,0><<<dim3(16,256,1), 64, 0, stream>>>(sn,256,0,0, Wf1T,256,0,0,
      bf1, nullptr,0,0,0, h1,1024,0,0, 256, 1, 1);
  gemm_kernel<2,4,0,1,0,0><<<dim3(4,256,1), 64, 0, stream>>>(h1,1024,0,0, Wf2T,1024,0,0,
      bf2, s2,256,0,0, outS,256,0,0, 1024, 1, 1);

  // --- vector FFN: norm2 -> hid GEMM -> out GEMM (+resid, interleaved store) ---
  vnorm2_kernel<<<8192, 192, 0, stream>>>(v2X, vs2, vn2X);
  gemm_kernel<2,4,0,0,0,0><<<dim3(4,768,1), 64, 0, stream>>>(vn2X,64,0,0, Wfv1T,64,0,0,
      nullptr, nullptr,0,0,0, hv,256,0,0, 64, 1, 1);
  gemm_kernel<2,4,0,1,0,1><<<dim3(1,768,1), 64, 0, stream>>>(hv,256,0,0, Wfv2T,256,0,0,
      nullptr, v2X,64,0,0, outV,0,0,0, 256, 1, 1);
}